// Round 15
// baseline (32.214 us; speedup 1.0000x reference)
//
#include <hip/hip_runtime.h>

constexpr int A_TOTAL = 5456;
constexpr int BATCH = 16;
constexpr int NUM_CLASSES = 80;
constexpr int NUM_CH = NUM_CLASSES + 2;   // 82
constexpr int MAX_OBJ = 32;
constexpr int LEVELS = 5;
constexpr int BINS = MAX_OBJ * LEVELS;    // 160
constexpr int BLK_L = 1024;               // 16 waves
constexpr int NSLOT = 16;                 // blocks per batch: 5456 = 16 * 341
constexpr int APB = A_TOTAL / NSLOT;      // 341 anchors per block (exact)
constexpr int PASS = BLK_L / 4;           // 256 anchors per pass (QPR=4)
constexpr float LN2 = 0.69314718056f;

__device__ __forceinline__ int lev_of(int a) {
    return (a < 4096) ? 0 : (a < 5120) ? 1 : (a < 5376) ? 2 : (a < 5440) ? 3 : 4;
}

// Focal partial in log2 domain (ln2 folded out; multiplied back once at end).
__device__ __forceinline__ float focal20(const float4* p4, const float4* t4) {
    float fl = 0.f;
    #pragma unroll
    for (int jj = 0; jj < 5; ++jj) {
        float ps[4] = {p4[jj].x, p4[jj].y, p4[jj].z, p4[jj].w};
        float ts[4] = {t4[jj].x, t4[jj].y, t4[jj].z, t4[jj].w};
        #pragma unroll
        for (int k = 0; k < 4; ++k) {
            float p  = fminf(fmaxf(ps[k], 1e-7f), 1.0f - 1e-7f);
            float tt = ts[k];
            float lp = __log2f(p);
            float lq = __log2f(1.0f - p);
            float ce2 = tt * (lp - lq) + lq;              // t*lp + (1-t)*lq
            float alpha_t = 0.75f - 0.5f * tt;            // t*0.25 + (1-t)*0.75
            float pt = tt * (1.0f - 2.0f * p) + p;        // t*(1-p) + (1-t)*p
            fl += alpha_t * pt * pt * ce2;                // (negated; *ln2 at end)
        }
    }
    return fl;
}

// Single dispatch (+1 tiny memset). Coherence recipe = EXACTLY R5's proven
// one: zeroed global bins, plain atomicAdd flush (device-scope RMW), counter
// trigger old==NSLOT-1 on zeroed counter, tail reads via atomicAdd(p,0.0f),
// tail pos from read-only cls_tar. Loss body = R14's prefetched 2-pass.
__global__ void __launch_bounds__(BLK_L)
fused_dwlm_kernel(const float* __restrict__ cls_pred,
                  const float* __restrict__ loc_pred,
                  const float* __restrict__ cls_tar,
                  const float* __restrict__ loc_tar,
                  const int*   __restrict__ ind_tar,
                  const int*   __restrict__ bbox_cnt,
                  float* __restrict__ g_sum,            // [B][BINS] zeroed per launch
                  float* __restrict__ g_cnt,            // [B][BINS] zeroed per launch
                  unsigned int* __restrict__ counters,  // [B]       zeroed per launch
                  float* __restrict__ out) {
    __shared__ float s_sum[BINS];
    __shared__ float s_cnt[BINS];
    __shared__ float s_tgt[BINS];
    __shared__ int   s_last;
    const int t = threadIdx.x;
    if (t < BINS) { s_sum[t] = 0.f; s_cnt[t] = 0.f; }
    __syncthreads();

    const int b = blockIdx.y;
    const int j = blockIdx.x;     // chunk within batch
    const int q = t & 3;          // quarter-row id
    const int r = t >> 2;         // anchor slot within pass (0..255)

    const int a1 = j * APB + r;           // pass-1 anchor (r<256<=341: always valid)
    const int a2 = a1 + PASS;             // pass-2 anchor
    const bool v2 = (r + PASS) < APB;     // r < 85
    const size_t row1 = (size_t)b * A_TOTAL + a1;
    const size_t row2 = row1 + PASS;

    // ---- issue ALL loads for both passes before any compute (R14-proven) ----
    const char* predb = (const char*)cls_pred;
    const char* tarb  = (const char*)cls_tar;
    float4 p4a[5], t4a[5], p4b[5], t4b[5];
    {
        const float4* pp1 = (const float4*)(predb + row1 * 320 + q * 16);
        const float4* tt1 = (const float4*)(tarb  + row1 * 328 + q * 16);
        #pragma unroll
        for (int jj = 0; jj < 5; ++jj) { p4a[jj] = pp1[jj * 4]; t4a[jj] = tt1[jj * 4]; }
    }
    float4 T1, P1, T2, P2;
    float pos1 = 0.f, pos2 = 0.f;
    T1 = ((const float4*)(loc_tar  + row1 * 4))[0];
    P1 = ((const float4*)(loc_pred + row1 * 4))[0];
    pos1 = cls_tar[row1 * NUM_CH + (NUM_CH - 1)];
    if (v2) {
        const float4* pp2 = (const float4*)(predb + row2 * 320 + q * 16);
        const float4* tt2 = (const float4*)(tarb  + row2 * 328 + q * 16);
        #pragma unroll
        for (int jj = 0; jj < 5; ++jj) { p4b[jj] = pp2[jj * 4]; t4b[jj] = tt2[jj * 4]; }
        T2 = ((const float4*)(loc_tar  + row2 * 4))[0];
        P2 = ((const float4*)(loc_pred + row2 * 4))[0];
        pos2 = cls_tar[row2 * NUM_CH + (NUM_CH - 1)];
    }

    // ---- pass 1 compute ----
    float fl = focal20(p4a, t4a);
    fl += __shfl_xor(fl, 1);
    fl += __shfl_xor(fl, 2);
    if (q == 0) {
        out[(size_t)BATCH * A_TOTAL + row1] = pos1;        // output 1: [B, A]
        float area_t = (T1.x + T1.z) * (T1.y + T1.w);
        float area_p = (P1.x + P1.z) * (P1.y + P1.w);
        float inter  = (fminf(T1.x, P1.x) + fminf(T1.z, P1.z)) * (fminf(T1.y, P1.y) + fminf(T1.w, P1.w));
        float uni    = area_t + area_p - inter;
        float iou    = inter / fmaxf(uni, 1e-7f);
        float enc    = (fmaxf(T1.x, P1.x) + fmaxf(T1.z, P1.z)) * (fmaxf(T1.y, P1.y) + fmaxf(T1.w, P1.w));
        float giou   = iou - (enc - uni) / fmaxf(enc, 1e-7f);
        float loss   = (1.f - giou) - LN2 * fl;
        int bin = ind_tar[row1] * LEVELS + lev_of(a1);
        atomicAdd(&s_sum[bin], loss);
        atomicAdd(&s_cnt[bin], 1.0f);
    }

    // ---- pass 2 compute ----
    if (v2) {
        float fl2 = focal20(p4b, t4b);
        fl2 += __shfl_xor(fl2, 1);
        fl2 += __shfl_xor(fl2, 2);
        if (q == 0) {
            out[(size_t)BATCH * A_TOTAL + row2] = pos2;
            float area_t = (T2.x + T2.z) * (T2.y + T2.w);
            float area_p = (P2.x + P2.z) * (P2.y + P2.w);
            float inter  = (fminf(T2.x, P2.x) + fminf(T2.z, P2.z)) * (fminf(T2.y, P2.y) + fminf(T2.w, P2.w));
            float uni    = area_t + area_p - inter;
            float iou    = inter / fmaxf(uni, 1e-7f);
            float enc    = (fmaxf(T2.x, P2.x) + fmaxf(T2.z, P2.z)) * (fmaxf(T2.y, P2.y) + fmaxf(T2.w, P2.w));
            float giou   = iou - (enc - uni) / fmaxf(enc, 1e-7f);
            float loss   = (1.f - giou) - LN2 * fl2;
            int bin = ind_tar[row2] * LEVELS + lev_of(a2);
            atomicAdd(&s_sum[bin], loss);
            atomicAdd(&s_cnt[bin], 1.0f);
        }
    }
    __syncthreads();

    // ---- flush LDS hist to global bins (R5-proven: plain atomicAdd RMW) ----
    if (t < BINS) {
        float c = s_cnt[t];
        if (c != 0.f) {
            atomicAdd(&g_sum[b * BINS + t], s_sum[t]);
            atomicAdd(&g_cnt[b * BINS + t], c);
        }
    }
    // __syncthreads() drains each wave's vmem before the counter bump.
    __syncthreads();
    if (t == 0) {
        unsigned int old = atomicAdd(&counters[b], 1u);
        s_last = (old == NSLOT - 1);      // counters zeroed by captured memset
    }
    __syncthreads();
    if (!s_last) return;

    // ---- tail: last-arriving block of batch b (16 tails run on 16 CUs) ----
    if (t < BINS) {
        float s = atomicAdd(&g_sum[b * BINS + t], 0.0f);   // coherent RMW read
        float c = atomicAdd(&g_cnt[b * BINS + t], 0.0f);
        s_sum[t] = s / fmaxf(1.0f, c);                     // reuse s_sum as mean
    }
    __syncthreads();

    if (t < MAX_OBJ) {
        float mean[LEVELS];
        float mx = -1e30f;
        #pragma unroll
        for (int l = 0; l < LEVELS; ++l) {
            mean[l] = s_sum[t * LEVELS + l];
            mx = fmaxf(mx, mean[l]);
        }
        float lmax = mx + 1e-5f;
        float mn = 1e30f;
        #pragma unroll
        for (int l = 0; l < LEVELS; ++l) {
            if (mean[l] == 0.0f) mean[l] = lmax;
            mn = fminf(mn, mean[l]);
        }
        float denom = lmax - mn;
        float tgt[LEVELS];
        float m1 = -1e30f, m2 = -1e30f, m3 = -1e30f;
        #pragma unroll
        for (int l = 0; l < LEVELS; ++l) {
            float v = 1.0f - (mean[l] - mn) / denom;
            tgt[l] = v;
            if (v > m1)      { m3 = m2; m2 = m1; m1 = v; }
            else if (v > m2) { m3 = m2; m2 = v; }
            else if (v > m3) { m3 = v; }
        }
        const bool vld = t < bbox_cnt[b];
        #pragma unroll
        for (int l = 0; l < LEVELS; ++l) {
            float v = tgt[l];
            v = (v >= m3) ? v : 0.0f;
            s_tgt[t * LEVELS + l] = vld ? v : 0.0f;
        }
    }
    __syncthreads();

    // dense gather of the whole batch, manual prefetch (6 rounds of 1024 thr);
    // pos from read-only cls_tar (L2/L3-hot from phase 1), ind coalesced.
    {
        float posv[6];
        int   ov[6], av[6];
        int n = 0;
        for (int a3 = t; a3 < A_TOTAL; a3 += BLK_L) {
            const size_t r3 = (size_t)b * A_TOTAL + a3;
            posv[n] = cls_tar[r3 * NUM_CH + (NUM_CH - 1)];
            ov[n]   = ind_tar[r3];
            av[n]   = a3;
            ++n;
        }
        for (int i = 0; i < n; ++i) {
            const size_t r3 = (size_t)b * A_TOTAL + av[i];
            out[r3] = (posv[i] > 0.0f) ? s_tgt[ov[i] * LEVELS + lev_of(av[i])] : 1.0f;
        }
    }
}

extern "C" void kernel_launch(void* const* d_in, const int* in_sizes, int n_in,
                              void* d_out, int out_size, void* d_ws, size_t ws_size,
                              hipStream_t stream) {
    const float* cls_pred = (const float*)d_in[0];
    const float* loc_pred = (const float*)d_in[1];
    const float* cls_tar  = (const float*)d_in[2];
    const float* loc_tar  = (const float*)d_in[3];
    const int*   ind_tar  = (const int*)d_in[4];
    const int*   bbox_cnt = (const int*)d_in[5];
    float* out = (float*)d_out;

    float* g_sum = (float*)d_ws;                            // [16][160]
    float* g_cnt = g_sum + (size_t)BATCH * BINS;            // [16][160]
    unsigned int* counters = (unsigned int*)(g_cnt + (size_t)BATCH * BINS);  // [16]

    // zero bins + counters each launch (captured into the graph, replayed)
    hipMemsetAsync(d_ws, 0,
                   (2 * BATCH * BINS) * sizeof(float) + BATCH * sizeof(unsigned int),
                   stream);

    fused_dwlm_kernel<<<dim3(NSLOT, BATCH), dim3(BLK_L), 0, stream>>>(
        cls_pred, loc_pred, cls_tar, loc_tar, ind_tar, bbox_cnt,
        g_sum, g_cnt, counters, out);
}

// Round 16
// 20.059 us; speedup vs baseline: 1.6060x; 1.6060x over previous
//
#include <hip/hip_runtime.h>

constexpr int A_TOTAL = 5456;
constexpr int BATCH = 16;
constexpr int NUM_CH = 82;
constexpr int MAX_OBJ = 32;
constexpr int LEVELS = 5;
constexpr int BINS = MAX_OBJ * LEVELS;    // 160
constexpr int BLK_L = 1024;               // 16 waves
constexpr int NSLOT = 32;                 // chunks per batch -> grid 512 = 2 blocks/CU
constexpr int CH = 171;                   // anchors per chunk (last chunk: 155)
constexpr int PASS = BLK_L / 8;           // 128 anchors per pass (QPR=8)
constexpr int BLK_G = 256;                // gather block
constexpr int NBLK_G = (A_TOTAL + BLK_G - 1) / BLK_G;  // 22
constexpr float LN2 = 0.69314718056f;

__device__ __forceinline__ int lev_of(int a) {
    return (a < 4096) ? 0 : (a < 5120) ? 1 : (a < 5376) ? 2 : (a < 5440) ? 3 : 4;
}

// 10-class focal partial in log2 domain (x ln2 folded back once at the end).
__device__ __forceinline__ float focal10(const float2* pv, const float2* tv) {
    float fl = 0.f;
    #pragma unroll
    for (int jj = 0; jj < 5; ++jj) {
        float ps[2] = {pv[jj].x, pv[jj].y};
        float ts[2] = {tv[jj].x, tv[jj].y};
        #pragma unroll
        for (int k = 0; k < 2; ++k) {
            float p  = fminf(fmaxf(ps[k], 1e-7f), 1.0f - 1e-7f);
            float tt = ts[k];
            float lp = __log2f(p);
            float lq = __log2f(1.0f - p);
            float ce2 = tt * (lp - lq) + lq;
            float alpha_t = 0.75f - 0.5f * tt;
            float pt = tt * (1.0f - 2.0f * p) + p;
            fl += alpha_t * pt * pt * ce2;
        }
    }
    return fl;
}

// Loss kernel, R16: QPR=8 (10 classes/lane as 5 x float2, always 8B-aligned),
// VGPR<=64 via __launch_bounds__(1024,8) -> 32 waves/CU with the 512-block
// grid (2 blocks/CU). TLP doubled vs R12-R14 (which were all 16 waves/CU).
__global__ void __launch_bounds__(BLK_L, 8)
loss_accum_kernel(const float* __restrict__ cls_pred,
                  const float* __restrict__ loc_pred,
                  const float* __restrict__ cls_tar,
                  const float* __restrict__ loc_tar,
                  const int*   __restrict__ ind_tar,
                  float* __restrict__ p_sum,   // [B][NSLOT][BINS]
                  float* __restrict__ p_cnt,   // [B][NSLOT][BINS]
                  float* __restrict__ out) {
    __shared__ float s_sum[BINS];
    __shared__ float s_cnt[BINS];
    const int t = threadIdx.x;
    if (t < BINS) { s_sum[t] = 0.f; s_cnt[t] = 0.f; }
    __syncthreads();

    const int b = blockIdx.y;
    const int j = blockIdx.x;            // chunk within batch
    const int h = t & 7;                 // eighth-row id (classes 10h..10h+9)
    const int rr = t >> 3;               // anchor slot within pass (0..127)
    const int lim = min(CH, A_TOTAL - j * CH);   // 171, or 155 for j==31

    const char* predb = (const char*)cls_pred;
    const char* tarb  = (const char*)cls_tar;

    #pragma unroll
    for (int base = 0; base < CH; base += PASS) {
        const int al = base + rr;
        const bool valid = al < lim;

        float2 pv[5], tv[5];
        float4 T, P;
        float  pos = 0.f;
        size_t row = 0;
        int a = 0;

        if (valid) {
            a = j * CH + al;
            row = (size_t)b * A_TOTAL + a;
            const char* pb = predb + row * 320 + h * 40;
            const char* tb = tarb  + row * 328 + h * 40;
            #pragma unroll
            for (int jj = 0; jj < 5; ++jj) {
                pv[jj] = *(const float2*)(pb + 8 * jj);
                tv[jj] = *(const float2*)(tb + 8 * jj);
            }
            if (h == 0) {
                T   = ((const float4*)(loc_tar  + row * 4))[0];
                P   = ((const float4*)(loc_pred + row * 4))[0];
                pos = cls_tar[row * NUM_CH + (NUM_CH - 1)];
            }
        }

        float fl = valid ? focal10(pv, tv) : 0.f;
        // reduce the 8 eighth-row partials (8-lane clusters are wave-aligned)
        fl += __shfl_xor(fl, 1);
        fl += __shfl_xor(fl, 2);
        fl += __shfl_xor(fl, 4);

        if (valid && h == 0) {
            out[(size_t)BATCH * A_TOTAL + row] = pos;        // output 1: [B, A]
            float area_t = (T.x + T.z) * (T.y + T.w);
            float area_p = (P.x + P.z) * (P.y + P.w);
            float inter  = (fminf(T.x, P.x) + fminf(T.z, P.z)) * (fminf(T.y, P.y) + fminf(T.w, P.w));
            float uni    = area_t + area_p - inter;
            float iou    = inter / fmaxf(uni, 1e-7f);
            float enc    = (fmaxf(T.x, P.x) + fmaxf(T.z, P.z)) * (fmaxf(T.y, P.y) + fmaxf(T.w, P.w));
            float giou   = iou - (enc - uni) / fmaxf(enc, 1e-7f);
            float loss   = (1.f - giou) - LN2 * fl;
            int bin = ind_tar[row] * LEVELS + lev_of(a);
            atomicAdd(&s_sum[bin], loss);
            atomicAdd(&s_cnt[bin], 1.0f);
        }
    }

    __syncthreads();
    if (t < BINS) {
        const size_t slot = ((size_t)b * NSLOT + j) * BINS + t;
        p_sum[slot] = s_sum[t];
        p_cnt[slot] = s_cnt[t];
    }
}

// Gather kernel (proven): reduce this batch's 32 slots (L2-hot) -> per-(o,l)
// target -> scatter to anchors; pos staged in d_out by the loss kernel.
__global__ void __launch_bounds__(BLK_G)
gather_kernel(const float* __restrict__ p_sum,
              const float* __restrict__ p_cnt,
              const int*   __restrict__ ind_tar,
              const int*   __restrict__ bbox_cnt,
              float* __restrict__ out) {
    __shared__ float s_mean[BINS];
    __shared__ float s_tgt[BINS];
    const int t = threadIdx.x;
    const int b = blockIdx.y;

    if (t < BINS) {
        float s = 0.f, c = 0.f;
        const size_t base = (size_t)b * NSLOT * BINS + t;
        #pragma unroll 8
        for (int k = 0; k < NSLOT; ++k) {
            s += p_sum[base + (size_t)k * BINS];
            c += p_cnt[base + (size_t)k * BINS];
        }
        s_mean[t] = s / fmaxf(1.0f, c);
    }
    __syncthreads();

    if (t < MAX_OBJ) {
        float mean[LEVELS];
        float mx = -1e30f;
        #pragma unroll
        for (int l = 0; l < LEVELS; ++l) {
            mean[l] = s_mean[t * LEVELS + l];
            mx = fmaxf(mx, mean[l]);
        }
        float lmax = mx + 1e-5f;
        float mn = 1e30f;
        #pragma unroll
        for (int l = 0; l < LEVELS; ++l) {
            if (mean[l] == 0.0f) mean[l] = lmax;
            mn = fminf(mn, mean[l]);
        }
        float denom = lmax - mn;
        float tgt[LEVELS];
        float m1 = -1e30f, m2 = -1e30f, m3 = -1e30f;
        #pragma unroll
        for (int l = 0; l < LEVELS; ++l) {
            float v = 1.0f - (mean[l] - mn) / denom;
            tgt[l] = v;
            if (v > m1)      { m3 = m2; m2 = m1; m1 = v; }
            else if (v > m2) { m3 = m2; m2 = v; }
            else if (v > m3) { m3 = v; }
        }
        const bool valid = t < bbox_cnt[b];
        #pragma unroll
        for (int l = 0; l < LEVELS; ++l) {
            float v = tgt[l];
            v = (v >= m3) ? v : 0.0f;
            s_tgt[t * LEVELS + l] = valid ? v : 0.0f;
        }
    }
    __syncthreads();

    const int a = blockIdx.x * BLK_G + t;
    if (a >= A_TOTAL) return;
    const size_t row = (size_t)b * A_TOTAL + a;
    float pos = out[(size_t)BATCH * A_TOTAL + row];  // staged by loss kernel (dense)
    int o = ind_tar[row];
    out[row] = (pos > 0.0f) ? s_tgt[o * LEVELS + lev_of(a)] : 1.0f;
}

extern "C" void kernel_launch(void* const* d_in, const int* in_sizes, int n_in,
                              void* d_out, int out_size, void* d_ws, size_t ws_size,
                              hipStream_t stream) {
    const float* cls_pred = (const float*)d_in[0];
    const float* loc_pred = (const float*)d_in[1];
    const float* cls_tar  = (const float*)d_in[2];
    const float* loc_tar  = (const float*)d_in[3];
    const int*   ind_tar  = (const int*)d_in[4];
    const int*   bbox_cnt = (const int*)d_in[5];
    float* out = (float*)d_out;

    float* p_sum = (float*)d_ws;                        // [16][32][160]
    float* p_cnt = p_sum + (size_t)BATCH * NSLOT * BINS;

    loss_accum_kernel<<<dim3(NSLOT, BATCH), dim3(BLK_L), 0, stream>>>(
        cls_pred, loc_pred, cls_tar, loc_tar, ind_tar, p_sum, p_cnt, out);
    gather_kernel<<<dim3(NBLK_G, BATCH), dim3(BLK_G), 0, stream>>>(
        p_sum, p_cnt, ind_tar, bbox_cnt, out);
}